// Round 1
// baseline (35.296 us; speedup 1.0000x reference)
//
#include <hip/hip_runtime.h>

// MyMarginLoss: loss = sum_{b,m: mask_mentions} [ sum_c (mask_cand & c!=t) *
//                 max(0, 1.5 - (s[t] - s[c])) ] / (C-1)
// B=128, M=256, C=1024. Memory-bound streaming reduction.

constexpr int kC = 1024;
constexpr float kMargin = 1.5f;

__global__ __launch_bounds__(256)
void margin_rows_kernel(const float* __restrict__ source,
                        const int* __restrict__ target,
                        const int* __restrict__ mask_mentions,
                        const int* __restrict__ mask_candidates,
                        float* __restrict__ partials)
{
    const int row = blockIdx.x;
    // Masked mention: contributes 0. Write the partial (ws is poisoned, not
    // zeroed) and skip the 8 KB of row traffic entirely.
    if (mask_mentions[row] == 0) {
        if (threadIdx.x == 0) partials[row] = 0.0f;
        return;
    }
    const int t = target[row];
    const float* __restrict__ srow = source + (size_t)row * kC;
    const int*   __restrict__ mrow = mask_candidates + (size_t)row * kC;
    const float v_t = srow[t];  // same-address wave load -> one transaction

    // 256 threads x 4 elems = 1024: one float4 + one int4 per lane (32 B/lane).
    const int base = threadIdx.x * 4;
    const float4 s = *reinterpret_cast<const float4*>(srow + base);
    const int4   m = *reinterpret_cast<const int4*>(mrow + base);

    float acc = 0.0f;
    {
        const float sv[4] = {s.x, s.y, s.z, s.w};
        const int   mv[4] = {m.x, m.y, m.z, m.w};
        #pragma unroll
        for (int k = 0; k < 4; ++k) {
            const int c = base + k;
            const float h = fmaxf(0.0f, kMargin - (v_t - sv[k]));
            acc += (mv[k] != 0 && c != t) ? h : 0.0f;
        }
    }

    // wave-64 butterfly reduce
    #pragma unroll
    for (int off = 32; off > 0; off >>= 1)
        acc += __shfl_down(acc, off, 64);

    __shared__ float wsum[4];
    const int lane = threadIdx.x & 63;
    const int wid  = threadIdx.x >> 6;
    if (lane == 0) wsum[wid] = acc;
    __syncthreads();
    if (threadIdx.x == 0)
        partials[row] = wsum[0] + wsum[1] + wsum[2] + wsum[3];
}

// Deterministic final fold of the 32768 per-row partials (128 KB, L2-hot).
// One block: no atomics, no cross-block ordering dependence.
__global__ __launch_bounds__(1024)
void reduce_kernel(const float* __restrict__ partials, int n,
                   float* __restrict__ out)
{
    float acc = 0.0f;
    for (int i = threadIdx.x; i < n; i += 1024)
        acc += partials[i];
    #pragma unroll
    for (int off = 32; off > 0; off >>= 1)
        acc += __shfl_down(acc, off, 64);
    __shared__ float wsum[16];
    const int lane = threadIdx.x & 63;
    const int wid  = threadIdx.x >> 6;
    if (lane == 0) wsum[wid] = acc;
    __syncthreads();
    if (threadIdx.x == 0) {
        float tot = 0.0f;
        #pragma unroll
        for (int w = 0; w < 16; ++w) tot += wsum[w];
        out[0] = tot * (1.0f / (kC - 1));
    }
}

extern "C" void kernel_launch(void* const* d_in, const int* in_sizes, int n_in,
                              void* d_out, int out_size, void* d_ws, size_t ws_size,
                              hipStream_t stream) {
    const float* source          = (const float*)d_in[0];
    const int*   target          = (const int*)d_in[1];
    const int*   mask_mentions   = (const int*)d_in[2];
    const int*   mask_candidates = (const int*)d_in[3];
    const int n_rows = in_sizes[1];            // B*M = 32768
    float* partials = (float*)d_ws;            // 128 KB of scratch

    margin_rows_kernel<<<n_rows, 256, 0, stream>>>(
        source, target, mask_mentions, mask_candidates, partials);
    reduce_kernel<<<1, 1024, 0, stream>>>(partials, n_rows, (float*)d_out);
}

// Round 2
// 29.472 us; speedup vs baseline: 1.1976x; 1.1976x over previous
//
#include <hip/hip_runtime.h>

// MyMarginLoss: loss = sum_{b,m: mask_mentions} [ sum_c (mask_cand & c!=t) *
//                 max(0, 1.5 - (s[t] - s[c])) ] / (C-1)
// B=128, M=256, C=1024, fp32 source, int32 masks (harness-converted).
// Memory-bound streaming reduction: ~134 MB effective traffic (half the rows
// are mention-masked and skipped before their 8 KB is touched).

constexpr int kC = 1024;
constexpr float kMargin = 1.5f;
constexpr int kBlocks = 2048;          // x4 waves = 8192 waves = 256 CU * 32
constexpr int kWavesTotal = kBlocks * 4;

__global__ __launch_bounds__(256)
void margin_rows_kernel(const float* __restrict__ source,
                        const int* __restrict__ target,
                        const int* __restrict__ mask_mentions,
                        const int* __restrict__ mask_candidates,
                        float* __restrict__ partials,
                        int n_rows)
{
    const int lane = threadIdx.x & 63;
    const int wid  = threadIdx.x >> 6;
    const int gwave = blockIdx.x * 4 + wid;   // global wave id

    float acc = 0.0f;
    for (int row = gwave; row < n_rows; row += kWavesTotal) {
        if (mask_mentions[row] == 0) continue;   // broadcast load, skips 8 KB
        const int t = target[row];
        const float* __restrict__ srow = source + (size_t)row * kC;
        const int*   __restrict__ mrow = mask_candidates + (size_t)row * kC;
        const float v_t = srow[t];               // same-address wave load

        // 64 lanes x 4 reps x float4 = 1024 elems; each load = 1 KB contiguous.
        #pragma unroll
        for (int rep = 0; rep < 4; ++rep) {
            const int base = rep * 256 + lane * 4;
            const float4 s = *reinterpret_cast<const float4*>(srow + base);
            const int4   m = *reinterpret_cast<const int4*>(mrow + base);
            acc += (m.x != 0 && (base + 0) != t) ? fmaxf(0.0f, kMargin - (v_t - s.x)) : 0.0f;
            acc += (m.y != 0 && (base + 1) != t) ? fmaxf(0.0f, kMargin - (v_t - s.y)) : 0.0f;
            acc += (m.z != 0 && (base + 2) != t) ? fmaxf(0.0f, kMargin - (v_t - s.z)) : 0.0f;
            acc += (m.w != 0 && (base + 3) != t) ? fmaxf(0.0f, kMargin - (v_t - s.w)) : 0.0f;
        }
    }

    // one wave-64 butterfly + one LDS combine per BLOCK (not per row)
    #pragma unroll
    for (int off = 32; off > 0; off >>= 1)
        acc += __shfl_down(acc, off, 64);

    __shared__ float wsum[4];
    if (lane == 0) wsum[wid] = acc;
    __syncthreads();
    if (threadIdx.x == 0)
        partials[blockIdx.x] = wsum[0] + wsum[1] + wsum[2] + wsum[3];
}

// Deterministic final fold of the 2048 per-block partials (8 KB, L2-hot).
__global__ __launch_bounds__(256)
void reduce_kernel(const float* __restrict__ partials, int n,
                   float* __restrict__ out)
{
    float acc = 0.0f;
    for (int i = threadIdx.x; i < n; i += 256)
        acc += partials[i];
    #pragma unroll
    for (int off = 32; off > 0; off >>= 1)
        acc += __shfl_down(acc, off, 64);
    __shared__ float wsum[4];
    const int lane = threadIdx.x & 63;
    const int wid  = threadIdx.x >> 6;
    if (lane == 0) wsum[wid] = acc;
    __syncthreads();
    if (threadIdx.x == 0)
        out[0] = (wsum[0] + wsum[1] + wsum[2] + wsum[3]) * (1.0f / (kC - 1));
}

extern "C" void kernel_launch(void* const* d_in, const int* in_sizes, int n_in,
                              void* d_out, int out_size, void* d_ws, size_t ws_size,
                              hipStream_t stream) {
    const float* source          = (const float*)d_in[0];
    const int*   target          = (const int*)d_in[1];
    const int*   mask_mentions   = (const int*)d_in[2];
    const int*   mask_candidates = (const int*)d_in[3];
    const int n_rows = in_sizes[1];            // B*M = 32768
    float* partials = (float*)d_ws;            // 8 KB of scratch

    margin_rows_kernel<<<kBlocks, 256, 0, stream>>>(
        source, target, mask_mentions, mask_candidates, partials, n_rows);
    reduce_kernel<<<1, 256, 0, stream>>>(partials, kBlocks, (float*)d_out);
}